// Round 4
// baseline (22.221 us; speedup 1.0000x reference)
//
#include <hip/hip_runtime.h>
#include <math.h>

#define EPSC 1.1920928955078125e-07f
#define BATCH 8388608
#define IN_FEATS 2048
#define N_ROW_CHUNKS 16
#define ROWS_PER_CHUNK 64
#define N_W_BLOCKS 32                 // 2 col-halves x 16 row chunks, float4 loads
#define N_BCE_BLOCKS 2048
#define BCE_ITERS 4                   // (BATCH/4) / (N_BCE_BLOCKS*256)
#define TOTAL_BLOCKS (N_W_BLOCKS + N_BCE_BLOCKS)

__device__ __forceinline__ float penalty_f(float x) {
    return 1.0f - __expf(-x * x) + fabsf(x);
}

// One dispatch computes all partials. Blocks 0..31: float4 column sum-of-squares
// of W. Blocks 32..2079: BCE partials with all 8 float4 loads issued before any
// compute (ILP ~8 outstanding loads/thread).
__global__ __launch_bounds__(256) void partials_k(
        const float* __restrict__ p, const float* __restrict__ y,
        const float* __restrict__ W,
        float* __restrict__ colsq_part,   // [16][2048]
        float* __restrict__ bce_part) {   // [2048]
    const int b = blockIdx.x;
    const int t = threadIdx.x;

    if (b < N_W_BLOCKS) {
        const int cb    = b & 1;          // column half: 0 or 1
        const int chunk = b >> 1;         // 0..15
        const int colf4 = cb * 256 + t;   // float4 column index, 0..511
        const float4* base4 = (const float4*)W
                            + (size_t)chunk * ROWS_PER_CHUNK * (IN_FEATS / 4) + colf4;
        float4 a = {0.f, 0.f, 0.f, 0.f};
        #pragma unroll 8
        for (int r = 0; r < ROWS_PER_CHUNK; ++r) {
            float4 w = base4[(size_t)r * (IN_FEATS / 4)];
            a.x = fmaf(w.x, w.x, a.x);
            a.y = fmaf(w.y, w.y, a.y);
            a.z = fmaf(w.z, w.z, a.z);
            a.w = fmaf(w.w, w.w, a.w);
        }
        ((float4*)(colsq_part + chunk * IN_FEATS))[colf4] = a;
    } else {
        const int bb = b - N_W_BLOCKS;
        const float4* p4 = (const float4*)p;
        const float4* y4 = (const float4*)y;
        const int tid = bb * 256 + t;
        const int stride = N_BCE_BLOCKS * 256;    // 524288 float4 slots

        // Issue all loads first, then compute.
        float4 pv[BCE_ITERS], yv[BCE_ITERS];
        #pragma unroll
        for (int it = 0; it < BCE_ITERS; ++it) {
            int i = tid + it * stride;
            pv[it] = p4[i];
            yv[it] = y4[i];
        }
        float acc = 0.0f;
        #pragma unroll
        for (int it = 0; it < BCE_ITERS; ++it) {
            float pp[4] = {pv[it].x, pv[it].y, pv[it].z, pv[it].w};
            float yy[4] = {yv[it].x, yv[it].y, yv[it].z, yv[it].w};
            #pragma unroll
            for (int k = 0; k < 4; ++k) {
                // y is exactly 0.0 or 1.0: one BCE branch survives.
                bool pos = yy[k] > 0.5f;
                float x  = pos ? pp[k] : 1.0f - pp[k];
                float w  = pos ? 0.7f : 0.3f;
                float xc = fminf(fmaxf(x, EPSC), 1.0f - EPSC);
                acc -= w * __logf(xc);
            }
        }
        __shared__ float s[256];
        s[t] = acc;
        __syncthreads();
        #pragma unroll
        for (int o = 128; o > 0; o >>= 1) {
            if (t < o) s[t] += s[t + o];
            __syncthreads();
        }
        if (t == 0) bce_part[bb] = s[0];
    }
}

// Single 1024-thread block: 128 KB colsq partials + 8 KB BCE partials -> scalar.
__global__ __launch_bounds__(1024) void finalize_k(
        const float* __restrict__ bce_part,
        const float* __restrict__ colsq_part,
        float* __restrict__ out) {
    __shared__ float cn[IN_FEATS];
    const int t = threadIdx.x;

    #pragma unroll
    for (int j = 0; j < IN_FEATS / 1024; ++j) {     // 2 cols per thread
        int c = t + j * 1024;
        float sum = 0.0f;
        #pragma unroll
        for (int k = 0; k < N_ROW_CHUNKS; ++k) sum += colsq_part[k * IN_FEATS + c];
        cn[c] = sqrtf(sum);
    }
    __syncthreads();

    float reg = penalty_f(cn[1024 + t]);            // tail cols, 1 per thread
    if (t < 64) {                                   // 64 groups of 16
        float gs = 0.0f;
        #pragma unroll
        for (int k = 0; k < 16; ++k) gs += cn[t * 16 + k];
        reg += penalty_f(gs * (1.0f / 16.0f));
    }
    float bce = bce_part[t] + bce_part[t + 1024];   // 2048 partials

    __shared__ float sr[1024], sb[1024];
    sr[t] = reg;
    sb[t] = bce;
    __syncthreads();
    #pragma unroll
    for (int o = 512; o > 0; o >>= 1) {
        if (t < o) { sr[t] += sr[t + o]; sb[t] += sb[t + o]; }
        __syncthreads();
    }
    if (t == 0) {
        out[0] = sb[0] * (1.0f / (float)BATCH) + 0.01f * sr[0];
    }
}

extern "C" void kernel_launch(void* const* d_in, const int* in_sizes, int n_in,
                              void* d_out, int out_size, void* d_ws, size_t ws_size,
                              hipStream_t stream) {
    const float* p = (const float*)d_in[0];
    const float* y = (const float*)d_in[1];
    const float* W = (const float*)d_in[2];
    float* out = (float*)d_out;

    float* colsq = (float*)d_ws;                          // 16*2048 floats
    float* bcep  = colsq + N_ROW_CHUNKS * IN_FEATS;       // 2048 floats

    partials_k<<<TOTAL_BLOCKS, 256, 0, stream>>>(p, y, W, colsq, bcep);
    finalize_k<<<1, 1024, 0, stream>>>(bcep, colsq, out);
}